// Round 5
// baseline (9167.227 us; speedup 1.0000x reference)
//
#include <hip/hip_runtime.h>

#define TT 512
#define II 128
#define HH 1024
#define BB 64

typedef __attribute__((ext_vector_type(8))) short bf16x8;
typedef __attribute__((ext_vector_type(4))) float f32x4;

__device__ __forceinline__ unsigned short f2bf(float f) {
  unsigned u = __builtin_bit_cast(unsigned, f);
  u += 0x7fffu + ((u >> 16) & 1u);   // round-to-nearest-even
  return (unsigned short)(u >> 16);
}

__device__ __forceinline__ bf16x8 load8f_bf(const float* p) {
  const f32x4* q = (const f32x4*)p;
  f32x4 a = q[0];
  f32x4 b = q[1];
  bf16x8 r;
  r[0] = (short)f2bf(a[0]); r[1] = (short)f2bf(a[1]);
  r[2] = (short)f2bf(a[2]); r[3] = (short)f2bf(a[3]);
  r[4] = (short)f2bf(b[0]); r[5] = (short)f2bf(b[1]);
  r[6] = (short)f2bf(b[2]); r[7] = (short)f2bf(b[3]);
  return r;
}

__device__ __forceinline__ float sigm(float v) { return 1.f / (1.f + __expf(-v)); }
__device__ __forceinline__ float tanh_f(float v) { return 2.f / (1.f + __expf(-2.f * v)) - 1.f; }

// Monotonic group barrier, fan-in 128. Agent-scope release fence before
// arrival publishes this CU's writes; acquire fence after release
// invalidates L1/L2 before consuming. (Pattern verified rounds 1-4.)
__device__ __forceinline__ void group_barrier(int* bar, int g, int target) {
  __syncthreads();
  if (threadIdx.x == 0) {
    __builtin_amdgcn_fence(__ATOMIC_RELEASE, "agent");
    int* ctr  = bar + g * 64;
    int* flag = bar + g * 64 + 32;
    int v = __hip_atomic_fetch_add(ctr, 1, __ATOMIC_RELAXED, __HIP_MEMORY_SCOPE_AGENT);
    if (v == 127) {
      __hip_atomic_store(ctr, 0, __ATOMIC_RELAXED, __HIP_MEMORY_SCOPE_AGENT);
      __hip_atomic_store(flag, target, __ATOMIC_RELEASE, __HIP_MEMORY_SCOPE_AGENT);
    } else {
      while (__hip_atomic_load(flag, __ATOMIC_RELAXED, __HIP_MEMORY_SCOPE_AGENT) < target) {
        __builtin_amdgcn_s_sleep(2);
      }
    }
    __builtin_amdgcn_fence(__ATOMIC_ACQUIRE, "agent");
  }
  __syncthreads();
}

// 256 WGs x 256 threads (4 waves), 1 WG/CU. 2 groups x 128 WGs; group g owns
// batches [32g, 32g+32). WG owns 8 hidden units per layer (32 gate-rows each).
// Wave wv = K-quarter of BOTH layers; m-loop over 2 batch-tiles inside.
// Weights 100% resident: L0 all 18 frags + L1 first 6 kt (12 frags) in VGPRs
// (120 regs), L1 kt 6..15 (20 frags) in LDS (81.9 KB).
//
// WHY this shape (rounds 1-4 evidence): 512-thread WGs pin the VGPR budget
// at 128 and remat all weight loads (637 MB/launch LLC refetch = the 6 ms);
// launch_bounds/waves_per_eu cannot override it. 256-thread WGs demonstrably
// get 256 VGPRs (round 1), and with 116 KB LDS only 1 WG fits per CU anyway,
// so the scheduler has no occupancy reason to remat a ~180-reg ask.
__global__ __launch_bounds__(256, 1) void lstm_persistent(
    const float* __restrict__ x, const float* __restrict__ h0,
    const float* __restrict__ c0,
    const float* __restrict__ Wih0, const float* __restrict__ Whh0,
    const float* __restrict__ bih0, const float* __restrict__ bhh0,
    const float* __restrict__ Wih1, const float* __restrict__ Whh1,
    const float* __restrict__ bih1, const float* __restrict__ bhh1,
    const float* __restrict__ Wfc, const float* __restrict__ bfc,
    float* __restrict__ out, unsigned short* __restrict__ hbuf, int* __restrict__ bar)
{
  const int tid  = threadIdx.x;
  const int lane = tid & 63;
  const int wv   = tid >> 6;         // 0..3 = K-quarter
  const int bid  = blockIdx.x;
  const int g    = bid >> 7;         // group 0..1
  const int rank = bid & 127;        // 0..127
  const int gbase = g * 32;          // batch base
  const int ubase = rank * 8;        // unit base (both layers)

  unsigned short* h1s = hbuf;                  // [2][64][1024] bf16, double-buffered
  unsigned short* h2s = hbuf + 2 * BB * HH;

  __shared__ float lds_part[4][64][33];        // [kwv][row: 32 L0 + 32 L1][batch pad33]
  __shared__ float lds_bias[64];
  __shared__ float lds_out[32];
  extern __shared__ __align__(16) unsigned short lds_w[];  // 4*20*64 frags *16B = 81920B

  const int n16 = lane & 15;
  const int ko  = (lane >> 4) * 8;

  // ---- pack weights (B-frag layout: lane holds W[n=lane&15][kt*32+ko+0..7]) ----
  bf16x8 w0[2][9];    // L0: 2 n-tiles x 9 kt (K-quarter = 288)
  bf16x8 w1r[2][6];   // L1: 2 n-tiles x first 6 of 16 kt (K-quarter = 512)
#pragma unroll
  for (int nt = 0; nt < 2; ++nt) {
    int r = nt * 16 + n16;                     // local row: unit=r>>2, gate=r&3
    int R = (r & 3) * HH + ubase + (r >> 2);   // global gate-row (i,f,g,o order)
#pragma unroll
    for (int kt = 0; kt < 9; ++kt) {
      int c = wv * 288 + kt * 32 + ko;         // col in [0,1152)
      const float* src = (c < II) ? (Wih0 + (size_t)R * II + c)
                                  : (Whh0 + (size_t)R * HH + (c - II));
      w0[nt][kt] = load8f_bf(src);
    }
#pragma unroll
    for (int kt = 0; kt < 16; ++kt) {
      int c = wv * 512 + kt * 32 + ko;         // col in [0,2048)
      const float* src = (c < HH) ? (Wih1 + (size_t)R * HH + c)
                                  : (Whh1 + (size_t)R * HH + (c - HH));
      bf16x8 f = load8f_bf(src);
      if (kt < 6) {
        w1r[nt][kt] = f;
      } else {
        ((bf16x8*)lds_w)[(wv * 20 + nt * 10 + (kt - 6)) * 64 + lane] = f;
      }
    }
  }

  // combined biases -> LDS (rows 0..31 L0, 32..63 L1)
  if (tid < 64) {
    int Lr = tid >> 5, r = tid & 31;
    int R = (r & 3) * HH + ubase + (r >> 2);
    lds_bias[tid] = (Lr == 0) ? (bih0[R] + bhh0[R]) : (bih1[R] + bhh1[R]);
  }

  // epilogue mapping: 256 threads = 2 layers x 8 units x 16 batch-pairs
  const int eL  = tid >> 7;
  const int eu  = (tid >> 4) & 7;
  const int em0 = (tid & 15) * 2;
  const int u_e = ubase + eu;
  const int b0_e = gbase + em0;
  float c_a = c0[eL * BB * HH + (size_t)b0_e * HH + u_e];
  float c_b = c0[eL * BB * HH + (size_t)(b0_e + 1) * HH + u_e];
  const float wfc_r = Wfc[u_e];

  // init h double-buffers: slot 1 <- h0 (read at p=0 / p=1)
  if (rank < 32) {
    int b = gbase + rank;
    for (int u = tid; u < HH; u += 256) {
      h1s[BB * HH + b * HH + u] = f2bf(h0[0 * BB * HH + b * HH + u]);
      h2s[BB * HH + b * HH + u] = f2bf(h0[1 * BB * HH + b * HH + u]);
    }
  }
  // init out with b_fc (atomics accumulate onto it)
  if (rank == 0) {
    float bf = bfc[0];
    for (int i = tid; i < 32 * TT; i += 256)
      out[(gbase + (i >> 9)) * TT + (i & 511)] = bf;
  }

  group_barrier(bar, g, 1);

  for (int p = 0; p <= TT; ++p) {
    const bool l0act = (p < TT);
    const bool l1act = (p >= 1);
    const unsigned short* h1r = h1s + ((p - 1) & 1) * (BB * HH);  // h1[p-1]
    const unsigned short* h2r = h2s + (p & 1) * (BB * HH);        // h2[p-2]
    const int mbase = (lane >> 4) * 4;

    // ---- layer 0: A = [x[p] | h1[p-1]], K-quarter of 1152 ----
    if (l0act) {
#pragma unroll
      for (int m = 0; m < 2; ++m) {
        const int bA = gbase + m * 16 + n16;
        f32x4 a0 = (f32x4){0.f, 0.f, 0.f, 0.f};
        f32x4 a1 = (f32x4){0.f, 0.f, 0.f, 0.f};
#pragma unroll
        for (int kt = 0; kt < 9; ++kt) {
          int c = wv * 288 + kt * 32 + ko;
          bf16x8 a = (c < II)
            ? load8f_bf(x + ((size_t)bA * TT + p) * II + c)
            : *(const bf16x8*)(h1r + (size_t)bA * HH + (c - II));
          a0 = __builtin_amdgcn_mfma_f32_16x16x32_bf16(a, w0[0][kt], a0, 0, 0, 0);
          a1 = __builtin_amdgcn_mfma_f32_16x16x32_bf16(a, w0[1][kt], a1, 0, 0, 0);
        }
        const int mc = m * 16 + mbase;
#pragma unroll
        for (int r = 0; r < 4; ++r) {
          lds_part[wv][n16][mc + r]      = a0[r];
          lds_part[wv][16 + n16][mc + r] = a1[r];
        }
      }
    }
    // ---- layer 1: A = [h1[p-1] | h2[p-2]], K-quarter of 2048 ----
    if (l1act) {
      const unsigned short* hb = (wv < 2) ? h1r : h2r;
      const int kbase = (wv & 1) * 512;
#pragma unroll
      for (int m = 0; m < 2; ++m) {
        const int bA = gbase + m * 16 + n16;
        const unsigned short* abase = hb + (size_t)bA * HH + kbase + ko;
        f32x4 b0 = (f32x4){0.f, 0.f, 0.f, 0.f};
        f32x4 b1 = (f32x4){0.f, 0.f, 0.f, 0.f};
#pragma unroll
        for (int kt = 0; kt < 6; ++kt) {
          bf16x8 a = *(const bf16x8*)(abase + kt * 32);
          b0 = __builtin_amdgcn_mfma_f32_16x16x32_bf16(a, w1r[0][kt], b0, 0, 0, 0);
          b1 = __builtin_amdgcn_mfma_f32_16x16x32_bf16(a, w1r[1][kt], b1, 0, 0, 0);
        }
#pragma unroll
        for (int kt = 6; kt < 16; ++kt) {
          bf16x8 a = *(const bf16x8*)(abase + kt * 32);
          bf16x8 wa = ((const bf16x8*)lds_w)[(wv * 20 + (kt - 6)) * 64 + lane];
          bf16x8 wb = ((const bf16x8*)lds_w)[(wv * 20 + 10 + (kt - 6)) * 64 + lane];
          b0 = __builtin_amdgcn_mfma_f32_16x16x32_bf16(a, wa, b0, 0, 0, 0);
          b1 = __builtin_amdgcn_mfma_f32_16x16x32_bf16(a, wb, b1, 0, 0, 0);
        }
        const int mc = m * 16 + mbase;
#pragma unroll
        for (int r = 0; r < 4; ++r) {
          lds_part[wv][32 + n16][mc + r] = b0[r];
          lds_part[wv][48 + n16][mc + r] = b1[r];
        }
      }
    }
    if (tid < 32) lds_out[tid] = 0.f;
    __syncthreads();

    // ---- epilogue: reduce 4 K-quarters, activations, state update ----
    const bool eact = (eL == 0) ? l0act : l1act;
    if (eact) {
      const int rb = eL * 32 + eu * 4;
#pragma unroll
      for (int j = 0; j < 2; ++j) {
        const int em = em0 + j;
        float pre[4];
#pragma unroll
        for (int q = 0; q < 4; ++q) {
          float s = lds_bias[rb + q];
#pragma unroll
          for (int w2 = 0; w2 < 4; ++w2)
            s += lds_part[w2][rb + q][em];
          pre[q] = s;
        }
        float iv = sigm(pre[0]);
        float fv = sigm(pre[1]);
        float gv = tanh_f(pre[2]);
        float ov = sigm(pre[3]);
        float cc = j ? c_b : c_a;
        cc = fv * cc + iv * gv;
        float hv = ov * tanh_f(cc);
        if (j) c_b = cc; else c_a = cc;
        const int b = gbase + em;
        if (eL == 0) {
          h1s[(p & 1) * (BB * HH) + (size_t)b * HH + u_e] = f2bf(hv);        // h1[p]
        } else {
          h2s[((p - 1) & 1) * (BB * HH) + (size_t)b * HH + u_e] = f2bf(hv);  // h2[p-1]
          atomicAdd(&lds_out[em], hv * wfc_r);                               // FC partial
        }
      }
    }
    __syncthreads();
    if (l1act && tid < 32)
      atomicAdd(&out[(gbase + tid) * TT + (p - 1)], lds_out[tid]);

    if (p < TT) group_barrier(bar, g, p + 2);
  }
}

extern "C" void kernel_launch(void* const* d_in, const int* in_sizes, int n_in,
                              void* d_out, int out_size, void* d_ws, size_t ws_size,
                              hipStream_t stream) {
  (void)in_sizes; (void)n_in; (void)out_size; (void)ws_size;
  hipMemsetAsync(d_ws, 0, 4096, stream);   // barrier counters/flags
  int* bar = (int*)d_ws;
  unsigned short* hbuf = (unsigned short*)((char*)d_ws + 4096);  // 512 KB h buffers
  hipLaunchKernelGGL(lstm_persistent, dim3(256), dim3(256), 81920, stream,
      (const float*)d_in[0], (const float*)d_in[1], (const float*)d_in[2],
      (const float*)d_in[3], (const float*)d_in[4], (const float*)d_in[5],
      (const float*)d_in[6], (const float*)d_in[7], (const float*)d_in[8],
      (const float*)d_in[9], (const float*)d_in[10], (const float*)d_in[11],
      (const float*)d_in[12], (float*)d_out, hbuf, bar);
}